// Round 2
// baseline (700.004 us; speedup 1.0000x reference)
//
#include <hip/hip_runtime.h>
#include <cfloat>

// Problem constants
#define BS 16
#define CC 512
#define HWD 1024      // h*w
#define NN 16384      // BS*HWD rows
#define MM 8          // sub-codebooks
#define NE 1024       // codes per sub-codebook
#define ED 64         // code dim

// d_out layout (all read back as float32):
//   [0, 8388608)            z_vq  (bs,c,h,w)
//   [8388608]               loss
//   [8388609, 8519681)      min_encoding_indices (m*N), as float
//   [8519681, 8520705)      bin_count (n_e), as float
#define LOSS_OFF 8388608
#define IDX_OFF  8388609
#define BIN_OFF  8519681

// flag margin: ref fp32 quantization can perturb relative d_k by <=1.54e-5
#define TAU 4e-5f

// workspace byte offsets
#define WS_B    0             // float[MM*NE] emulated ||e||^2 (np pairwise)
#define WS_IDX  32768         // int[MM*NN]
#define WS_CNT  557056        // int flag counter
#define WS_LIST 557072        // int[MM*NN] flagged rows

// ---- fp32 ops with contraction disabled (bit-exact IEEE mul/add/sub) ------
__device__ __forceinline__ float mul_rn(float a, float b) {
#pragma clang fp contract(off)
    return a * b;
}
__device__ __forceinline__ float add_rn(float a, float b) {
#pragma clang fp contract(off)
    return a + b;
}
__device__ __forceinline__ float sub_rn(float a, float b) {
#pragma clang fp contract(off)
    return a - b;
}

// numpy FLOAT_pairwise_sum over fl(x_d^2), n=64: 8 accumulators seeded by
// x[0..7], 7 unrolled passes, combine ((r0+r1)+(r2+r3))+((r4+r5)+(r6+r7)).
__device__ __forceinline__ float np_sumsq64(const float* x) {
    float r[8];
#pragma unroll
    for (int j = 0; j < 8; ++j) r[j] = mul_rn(x[j], x[j]);
#pragma unroll
    for (int i = 8; i < 64; i += 8) {
#pragma unroll
        for (int j = 0; j < 8; ++j) r[j] = add_rn(r[j], mul_rn(x[i + j], x[i + j]));
    }
    return add_rn(add_rn(add_rn(r[0], r[1]), add_rn(r[2], r[3])),
                  add_rn(add_rn(r[4], r[5]), add_rn(r[6], r[7])));
}

// ---------------------------------------------------------------------------
// prep: emulated np ||e_k||^2 per (m,k)
__global__ __launch_bounds__(256) void prep_kernel(const float* __restrict__ cb,
                                                   float* __restrict__ Bhat) {
    int i = blockIdx.x * 256 + threadIdx.x;   // 0..MM*NE-1
    const float4* r4 = (const float4*)(cb + (size_t)i * ED);
    float x[ED];
#pragma unroll
    for (int q = 0; q < 16; ++q) {
        float4 v = r4[q];
        x[q * 4 + 0] = v.x; x[q * 4 + 1] = v.y; x[q * 4 + 2] = v.z; x[q * 4 + 3] = v.w;
    }
    Bhat[i] = np_sumsq64(x);
}

// ---------------------------------------------------------------------------
// phase 1: fast fp32 argmin (FMA ok, error ~5e-9) + top-2 margin flagging.
__global__ __launch_bounds__(256) void argmin_kernel(
        const float* __restrict__ z, const float* __restrict__ cb,
        const float* __restrict__ Bhat, int* __restrict__ idx_out,
        int* __restrict__ cnt, int* __restrict__ list) {
    const int tid = threadIdx.x;
    const int n = blockIdx.x * 256 + tid;
    const int m = blockIdx.y;
    const int b = n >> 10;
    const int hw = n & (HWD - 1);

    const float* zbase = z + (((size_t)(b * CC + m * ED)) << 10) + hw;
    float zr[ED];
#pragma unroll
    for (int d = 0; d < ED; ++d) zr[d] = zbase[(size_t)d << 10];

    __shared__ float tile[128 * ED];   // 32 KB
    const float* cbm = cb + (size_t)m * NE * ED;
    const float* en = Bhat + m * NE;

    float best = FLT_MAX, second = FLT_MAX;
    int bidx = 0;

    for (int kt = 0; kt < NE; kt += 128) {
        __syncthreads();
        const float4* src = (const float4*)(cbm + (size_t)kt * ED);
        float4* dst = (float4*)tile;
#pragma unroll
        for (int i = 0; i < 8; ++i) dst[tid + i * 256] = src[tid + i * 256];
        __syncthreads();

        for (int kk = 0; kk < 128; ++kk) {
            const float4* cr = (const float4*)(tile + kk * ED);
            float a0 = 0.f, a1 = 0.f, a2 = 0.f, a3 = 0.f;
#pragma unroll
            for (int d4 = 0; d4 < 16; ++d4) {
                float4 c = cr[d4];
                a0 += zr[d4 * 4 + 0] * c.x;
                a1 += zr[d4 * 4 + 1] * c.y;
                a2 += zr[d4 * 4 + 2] * c.z;
                a3 += zr[d4 * 4 + 3] * c.w;
            }
            float s = (a0 + a1) + (a2 + a3);
            float dist = en[kt + kk] - 2.0f * s;   // argmin-equivalent (drop ||z||^2)
            if (dist < best) { second = best; best = dist; bidx = kt + kk; }
            else if (dist < second) { second = dist; }
        }
    }
    idx_out[m * NN + n] = bidx;
    if (second - best < TAU) {
        int p = atomicAdd(cnt, 1);
        list[p] = m * NN + n;
    }
}

// ---------------------------------------------------------------------------
// phase 2: bit-exact numpy-fp32 pipeline emulation for flagged rows.
// One wave per row; lane j owns codes [16j, 16j+16) (ascending k with lane).
__global__ __launch_bounds__(256) void emul_kernel(
        const float* __restrict__ z, const float* __restrict__ cb,
        const float* __restrict__ Bhat, const int* __restrict__ cnt,
        const int* __restrict__ list, int* __restrict__ idx_out) {
    const int lane = threadIdx.x & 63;
    const int wid = (blockIdx.x * 256 + threadIdx.x) >> 6;
    const int nw = (gridDim.x * 256) >> 6;
    const int total = *cnt;
    for (int r = wid; r < total; r += nw) {
        const int mn = list[r];
        const int m = mn >> 14;          // NN = 2^14
        const int n = mn & (NN - 1);
        const int b = n >> 10;
        const int hw = n & (HWD - 1);
        const float* zbase = z + (((size_t)(b * CC + m * ED)) << 10) + hw;
        float zr[ED];
#pragma unroll
        for (int d = 0; d < ED; ++d) zr[d] = zbase[(size_t)d << 10];
        const float A = np_sumsq64(zr);

        const float* cbm = cb + (size_t)m * NE * ED;
        const float* Bm = Bhat + m * NE;
        float best = FLT_MAX;
        int bidx = NE;
        for (int kk = 0; kk < 16; ++kk) {
            const int k = lane * 16 + kk;
            const float4* cr4 = (const float4*)(cbm + (size_t)k * ED);
            // numpy einsum contig_outstride0_two, SSE npyv (nlanes=4, no FMA):
            // per 16-block: vacc_j = p(0+j) + (p(4+j) + (p(8+j) + (p(12+j)+vacc_j)))
            float v0 = 0.f, v1 = 0.f, v2 = 0.f, v3 = 0.f;
#pragma unroll
            for (int t = 0; t < 4; ++t) {
                float4 e0 = cr4[t * 4 + 0];   // y[16t+0..3]
                float4 e1 = cr4[t * 4 + 1];   // y[16t+4..7]
                float4 e2 = cr4[t * 4 + 2];   // y[16t+8..11]
                float4 e3 = cr4[t * 4 + 3];   // y[16t+12..15]
                const int d0 = 16 * t;
                v0 = add_rn(mul_rn(zr[d0 + 0], e0.x),
                     add_rn(mul_rn(zr[d0 + 4], e1.x),
                     add_rn(mul_rn(zr[d0 + 8], e2.x),
                     add_rn(mul_rn(zr[d0 + 12], e3.x), v0))));
                v1 = add_rn(mul_rn(zr[d0 + 1], e0.y),
                     add_rn(mul_rn(zr[d0 + 5], e1.y),
                     add_rn(mul_rn(zr[d0 + 9], e2.y),
                     add_rn(mul_rn(zr[d0 + 13], e3.y), v1))));
                v2 = add_rn(mul_rn(zr[d0 + 2], e0.z),
                     add_rn(mul_rn(zr[d0 + 6], e1.z),
                     add_rn(mul_rn(zr[d0 + 10], e2.z),
                     add_rn(mul_rn(zr[d0 + 14], e3.z), v2))));
                v3 = add_rn(mul_rn(zr[d0 + 3], e0.w),
                     add_rn(mul_rn(zr[d0 + 7], e1.w),
                     add_rn(mul_rn(zr[d0 + 11], e2.w),
                     add_rn(mul_rn(zr[d0 + 15], e3.w), v3))));
            }
            // SSE3 hadd finish: (v0+v1) + (v2+v3)
            float C = add_rn(add_rn(v0, v1), add_rn(v2, v3));
            // d = fl(fl(A + B_k) - fl(2*C))
            float dk = sub_rn(add_rn(A, Bm[k]), mul_rn(2.0f, C));
            if (dk < best) { best = dk; bidx = k; }   // ascending k: first wins
        }
        // cross-lane min, first-index tie-break (lower lane = lower k)
#pragma unroll
        for (int off = 32; off >= 1; off >>= 1) {
            float ov = __shfl_down(best, off, 64);
            int oi = __shfl_down(bidx, off, 64);
            if (ov < best || (ov == best && oi < bidx)) { best = ov; bidx = oi; }
        }
        if (lane == 0) idx_out[mn] = bidx;
    }
}

// ---------------------------------------------------------------------------
// Outputs: z_vq gather-scatter, indices as float, loss reduction, histogram.
__global__ __launch_bounds__(256) void output_kernel(
        const float* __restrict__ z, const float* __restrict__ cb,
        const int* __restrict__ idx_in, float* __restrict__ out) {
    const int tid = threadIdx.x;
    const int n = blockIdx.x * 256 + tid;
    const int m = blockIdx.y;
    const int b = n >> 10;
    const int hw = n & (HWD - 1);
    const int idx = idx_in[m * NN + n];

    out[IDX_OFF + m * NN + n] = (float)idx;

    const float* cr = cb + ((size_t)m * NE + (size_t)idx) * ED;
    const float* zbase = z + (((size_t)(b * CC + m * ED)) << 10) + hw;
    float* ob = out + (((size_t)(b * CC + m * ED)) << 10) + hw;

    double acc = 0.0;
#pragma unroll
    for (int d = 0; d < ED; ++d) {
        float c = cr[d];
        float zv = zbase[(size_t)d << 10];
        ob[(size_t)d << 10] = c;                 // STE forward value == zq
        float diff = c - zv;
        acc += (double)diff * (double)diff;
    }

    __shared__ int hist[NE];
#pragma unroll
    for (int i = 0; i < 4; ++i) hist[tid + i * 256] = 0;
    __syncthreads();
    atomicAdd(&hist[idx], 1);

    // loss = 1.25 * sum((zq - zf)^2) / (NN*ED)
#pragma unroll
    for (int off = 32; off >= 1; off >>= 1)
        acc += __shfl_down(acc, off, 64);
    __shared__ double wsum[4];
    if ((tid & 63) == 0) wsum[tid >> 6] = acc;
    __syncthreads();
    if (tid == 0) {
        double t = wsum[0] + wsum[1] + wsum[2] + wsum[3];
        atomicAdd(out + LOSS_OFF, (float)(t * (1.25 / 1048576.0)));
    }
#pragma unroll
    for (int i = 0; i < 4; ++i) {
        int v = hist[tid + i * 256];
        if (v) atomicAdd(out + BIN_OFF + tid + i * 256, (float)v);
    }
}

// ---------------------------------------------------------------------------
extern "C" void kernel_launch(void* const* d_in, const int* in_sizes, int n_in,
                              void* d_out, int out_size, void* d_ws, size_t ws_size,
                              hipStream_t stream) {
    const float* z = (const float*)d_in[0];    // (16,512,32,32) fp32
    const float* cb = (const float*)d_in[1];   // (8,1024,64) fp32
    float* out = (float*)d_out;
    char* ws = (char*)d_ws;
    float* Bhat = (float*)(ws + WS_B);
    int* idxw = (int*)(ws + WS_IDX);
    int* cnt = (int*)(ws + WS_CNT);
    int* list = (int*)(ws + WS_LIST);

    hipMemsetAsync(cnt, 0, 4, stream);
    hipMemsetAsync(out + LOSS_OFF, 0, 4, stream);
    hipMemsetAsync(out + BIN_OFF, 0, NE * sizeof(float), stream);

    prep_kernel<<<dim3(MM * NE / 256), dim3(256), 0, stream>>>(cb, Bhat);
    argmin_kernel<<<dim3(NN / 256, MM), dim3(256), 0, stream>>>(z, cb, Bhat,
                                                                idxw, cnt, list);
    emul_kernel<<<dim3(128), dim3(256), 0, stream>>>(z, cb, Bhat, cnt, list, idxw);
    output_kernel<<<dim3(NN / 256, MM), dim3(256), 0, stream>>>(z, cb, idxw, out);
}

// Round 3
// 343.195 us; speedup vs baseline: 2.0397x; 2.0397x over previous
//
#include <hip/hip_runtime.h>
#include <cfloat>

// Problem constants
#define BS 16
#define CC 512
#define HWD 1024      // h*w
#define NN 16384      // BS*HWD rows
#define MM 8          // sub-codebooks
#define NE 1024       // codes per sub-codebook
#define ED 64         // code dim

// d_out layout (all read back as float32):
//   [0, 8388608)            z_vq  (bs,c,h,w)
//   [8388608]               loss
//   [8388609, 8519681)      min_encoding_indices (m*N), as float
//   [8519681, 8520705)      bin_count (n_e), as float
#define LOSS_OFF 8388608
#define IDX_OFF  8388609
#define BIN_OFF  8519681

// flag margin: ref fp32 quantization perturbs d by <=~1.2e-5; phase-1 err ~5e-7
#define TAU 4e-5f

// workspace byte offsets
#define WS_B    0             // float[MM*NE] emulated ||e||^2 (np pairwise)
#define WS_IDX  32768         // int[MM*NN]
#define WS_CNT  557056        // int flag counter
#define WS_LIST 557072        // int[MM*NN] flagged rows
#define WS_BMAT 1081360       // uint4[8*12*32*64] = 3 MB, bf16 frag-order B

typedef __attribute__((ext_vector_type(8))) short bf16x8;
typedef __attribute__((ext_vector_type(16))) float f32x16;

// ---- bf16 helpers (manual RNE, no API dependency) -------------------------
__device__ __forceinline__ unsigned short f2bf(float f) {
    unsigned int u = __float_as_uint(f);
    unsigned int r = (u + 0x7fffu + ((u >> 16) & 1u)) >> 16;
    return (unsigned short)r;
}
__device__ __forceinline__ float bf2f(unsigned short h) {
    return __uint_as_float(((unsigned int)h) << 16);
}

// ---- fp32 ops with contraction disabled (bit-exact IEEE mul/add/sub) ------
__device__ __forceinline__ float mul_rn(float a, float b) {
#pragma clang fp contract(off)
    return a * b;
}
__device__ __forceinline__ float add_rn(float a, float b) {
#pragma clang fp contract(off)
    return a + b;
}
__device__ __forceinline__ float sub_rn(float a, float b) {
#pragma clang fp contract(off)
    return a - b;
}

// numpy FLOAT_pairwise_sum over fl(x_d^2), n=64
__device__ __forceinline__ float np_sumsq64(const float* x) {
    float r[8];
#pragma unroll
    for (int j = 0; j < 8; ++j) r[j] = mul_rn(x[j], x[j]);
#pragma unroll
    for (int i = 8; i < 64; i += 8) {
#pragma unroll
        for (int j = 0; j < 8; ++j) r[j] = add_rn(r[j], mul_rn(x[i + j], x[i + j]));
    }
    return add_rn(add_rn(add_rn(r[0], r[1]), add_rn(r[2], r[3])),
                  add_rn(add_rn(r[4], r[5]), add_rn(r[6], r[7])));
}

// ---------------------------------------------------------------------------
// prep: emulated np ||e_k||^2 per (m,k)  (used by emul AND as phase-1 norm)
__global__ __launch_bounds__(256) void prep_kernel(const float* __restrict__ cb,
                                                   float* __restrict__ Bhat) {
    int i = blockIdx.x * 256 + threadIdx.x;   // 0..MM*NE-1
    const float4* r4 = (const float4*)(cb + (size_t)i * ED);
    float x[ED];
#pragma unroll
    for (int q = 0; q < 16; ++q) {
        float4 v = r4[q];
        x[q * 4 + 0] = v.x; x[q * 4 + 1] = v.y; x[q * 4 + 2] = v.z; x[q * 4 + 3] = v.w;
    }
    Bhat[i] = np_sumsq64(x);
}

// ---------------------------------------------------------------------------
// prep_bmat: build B in MFMA-fragment order, split bf16 of (-2e).
// Bmat[t] for t = (((m*12 + c)*32 + ct)*64 + lane): one 16-B octet (8 bf16).
// K-chunk c: 0-3 -> eh (pairs with zh); 4-7 -> el (pairs with zh);
//            8-11 -> eh (pairs with zl).  k-within-chunk = 8*(lane>>5)+j.
__global__ __launch_bounds__(256) void prep_bmat(const float* __restrict__ cb,
                                                 uint4* __restrict__ Bmat) {
    int t = blockIdx.x * 256 + threadIdx.x;   // 0 .. 8*12*32*64-1
    int lane = t & 63;
    int ct = (t >> 6) & 31;
    int c = (t >> 11) % 12;
    int m = t / 24576;
    int h = lane >> 5;
    int k = ct * 32 + (lane & 31);            // code index
    int d0 = 16 * (c & 3) + 8 * h;            // dim base of this octet

    const float* e = cb + ((size_t)m * NE + k) * ED + d0;
    unsigned short v[8];
#pragma unroll
    for (int j = 0; j < 8; ++j) {
        float f = -2.0f * e[j];
        unsigned short hi = f2bf(f);
        if (c >= 4 && c < 8) {
            v[j] = f2bf(f - bf2f(hi));        // el
        } else {
            v[j] = hi;                        // eh
        }
    }
    uint4 o;
    o.x = (unsigned)v[0] | ((unsigned)v[1] << 16);
    o.y = (unsigned)v[2] | ((unsigned)v[3] << 16);
    o.z = (unsigned)v[4] | ((unsigned)v[5] << 16);
    o.w = (unsigned)v[6] | ((unsigned)v[7] << 16);
    Bmat[t] = o;
}

// ---------------------------------------------------------------------------
// phase 1: split-bf16 MFMA distance + per-row top-2 margin flagging.
// Block: 256 thr (4 waves), 128 rows (32/wave), all 1024 codes in 8 chunks.
__global__ __launch_bounds__(256, 2) void argmin_kernel(
        const float* __restrict__ z, const uint4* __restrict__ Bmat,
        const float* __restrict__ Bhat, int* __restrict__ idx_out,
        int* __restrict__ cnt, int* __restrict__ list) {
    const int tid = threadIdx.x;
    const int m = blockIdx.y;
    const int row0 = blockIdx.x * 128;
    const int w = tid >> 6;
    const int l = tid & 63;
    const int h = l >> 5;
    const int r5 = l & 31;

    __shared__ uint4 ldsB[12 * 256];     // 48 KB: [c][ctl][lane] 16-B frags
    __shared__ float ldsN[NE];           // 4 KB norms

    // stage norms
    {
        const float4* np4 = (const float4*)(Bhat + m * NE);
        ((float4*)ldsN)[tid] = np4[tid];
    }

    // load this lane's z row and split to bf16 hi/lo octets.
    // lane holds row n = row0 + w*32 + (l&31); octets o = 2*i + h.
    const int n_mine = row0 + w * 32 + r5;
    const int b = n_mine >> 10;
    const int hw = n_mine & (HWD - 1);
    const float* zbase = z + (((size_t)(b * CC + m * ED)) << 10) + hw;

    bf16x8 zh[4], zl[4];
#pragma unroll
    for (int i = 0; i < 4; ++i) {
        int o = 2 * i + h;
#pragma unroll
        for (int j = 0; j < 8; ++j) {
            float f = zbase[(size_t)(8 * o + j) << 10];
            unsigned short hb = f2bf(f);
            unsigned short lb = f2bf(f - bf2f(hb));
            zh[i][j] = (short)hb;
            zl[i][j] = (short)lb;
        }
    }

    float best[16], sec[16];
    int bidx[16];
#pragma unroll
    for (int s = 0; s < 16; ++s) { best[s] = FLT_MAX; sec[s] = FLT_MAX; bidx[s] = 0; }

    for (int cc = 0; cc < 8; ++cc) {      // col-chunks of 128 codes
        __syncthreads();
#pragma unroll
        for (int c = 0; c < 12; ++c) {
            const uint4* src = Bmat + ((size_t)(m * 12 + c) * 32 + cc * 4) * 64;
            ldsB[c * 256 + tid] = src[tid];
        }
        __syncthreads();

#pragma unroll
        for (int ctl = 0; ctl < 4; ++ctl) {  // col-tiles of 32 codes
            f32x16 acc;
#pragma unroll
            for (int s = 0; s < 16; ++s) acc[s] = 0.0f;

#pragma unroll
            for (int c = 0; c < 12; ++c) {
                bf16x8 bfrag = *(const bf16x8*)&ldsB[c * 256 + ctl * 64 + l];
                bf16x8 afrag = (c < 4) ? zh[c] : ((c < 8) ? zh[c - 4] : zl[c - 8]);
                acc = __builtin_amdgcn_mfma_f32_32x32x16_bf16(afrag, bfrag, acc,
                                                              0, 0, 0);
            }

            const int kcol = cc * 128 + ctl * 32 + r5;   // this lane's code col
            const float norm = ldsN[kcol];
#pragma unroll
            for (int s = 0; s < 16; ++s) {
                float d = acc[s] + norm;
                float t = fmaxf(best[s], d);
                sec[s] = fminf(sec[s], t);
                bool cdl = d < best[s];
                best[s] = fminf(best[s], d);
                bidx[s] = cdl ? kcol : bidx[s];
            }
        }
    }

    // cross-lane top-2 merge over the 32-lane half-group (same rows)
#pragma unroll
    for (int off = 1; off <= 16; off <<= 1) {
#pragma unroll
        for (int s = 0; s < 16; ++s) {
            float ob = __shfl_xor(best[s], off, 64);
            float os = __shfl_xor(sec[s], off, 64);
            int oi = __shfl_xor(bidx[s], off, 64);
            bool take = (ob < best[s]) || (ob == best[s] && oi < bidx[s]);
            float ns = take ? fminf(best[s], os) : fminf(sec[s], ob);
            best[s] = take ? ob : best[s];
            bidx[s] = take ? oi : bidx[s];
            sec[s] = ns;
        }
    }

    // lanes r5<16 write slot s=r5: row = (s&3) + 8*(s>>2) + 4*h  [m74/m101]
#pragma unroll
    for (int s = 0; s < 16; ++s) {
        if (r5 == s) {
            int row = (s & 3) + 8 * (s >> 2) + 4 * h;
            int n = row0 + w * 32 + row;
            int mn = m * NN + n;
            idx_out[mn] = bidx[s];
            if (sec[s] - best[s] < TAU) {
                int p = atomicAdd(cnt, 1);
                list[p] = mn;
            }
        }
    }
}

// ---------------------------------------------------------------------------
// phase 2: bit-exact numpy-fp32 pipeline emulation for flagged rows.
__global__ __launch_bounds__(256) void emul_kernel(
        const float* __restrict__ z, const float* __restrict__ cb,
        const float* __restrict__ Bhat, const int* __restrict__ cnt,
        const int* __restrict__ list, int* __restrict__ idx_out) {
    const int lane = threadIdx.x & 63;
    const int wid = (blockIdx.x * 256 + threadIdx.x) >> 6;
    const int nw = (gridDim.x * 256) >> 6;
    const int total = *cnt;
    for (int r = wid; r < total; r += nw) {
        const int mn = list[r];
        const int m = mn >> 14;          // NN = 2^14
        const int n = mn & (NN - 1);
        const int b = n >> 10;
        const int hw = n & (HWD - 1);
        const float* zbase = z + (((size_t)(b * CC + m * ED)) << 10) + hw;
        float zr[ED];
#pragma unroll
        for (int d = 0; d < ED; ++d) zr[d] = zbase[(size_t)d << 10];
        const float A = np_sumsq64(zr);

        const float* cbm = cb + (size_t)m * NE * ED;
        const float* Bm = Bhat + m * NE;
        float best = FLT_MAX;
        int bidx = NE;
        for (int kk = 0; kk < 16; ++kk) {
            const int k = lane * 16 + kk;
            const float4* cr4 = (const float4*)(cbm + (size_t)k * ED);
            // numpy einsum sum_of_products_contig_two, SSE npyv (no FMA)
            float v0 = 0.f, v1 = 0.f, v2 = 0.f, v3 = 0.f;
#pragma unroll
            for (int t = 0; t < 4; ++t) {
                float4 e0 = cr4[t * 4 + 0];
                float4 e1 = cr4[t * 4 + 1];
                float4 e2 = cr4[t * 4 + 2];
                float4 e3 = cr4[t * 4 + 3];
                const int d0 = 16 * t;
                v0 = add_rn(mul_rn(zr[d0 + 0], e0.x),
                     add_rn(mul_rn(zr[d0 + 4], e1.x),
                     add_rn(mul_rn(zr[d0 + 8], e2.x),
                     add_rn(mul_rn(zr[d0 + 12], e3.x), v0))));
                v1 = add_rn(mul_rn(zr[d0 + 1], e0.y),
                     add_rn(mul_rn(zr[d0 + 5], e1.y),
                     add_rn(mul_rn(zr[d0 + 9], e2.y),
                     add_rn(mul_rn(zr[d0 + 13], e3.y), v1))));
                v2 = add_rn(mul_rn(zr[d0 + 2], e0.z),
                     add_rn(mul_rn(zr[d0 + 6], e1.z),
                     add_rn(mul_rn(zr[d0 + 10], e2.z),
                     add_rn(mul_rn(zr[d0 + 14], e3.z), v2))));
                v3 = add_rn(mul_rn(zr[d0 + 3], e0.w),
                     add_rn(mul_rn(zr[d0 + 7], e1.w),
                     add_rn(mul_rn(zr[d0 + 11], e2.w),
                     add_rn(mul_rn(zr[d0 + 15], e3.w), v3))));
            }
            float C = add_rn(add_rn(v0, v1), add_rn(v2, v3));
            float dk = sub_rn(add_rn(A, Bm[k]), mul_rn(2.0f, C));
            if (dk < best) { best = dk; bidx = k; }
        }
#pragma unroll
        for (int off = 32; off >= 1; off >>= 1) {
            float ov = __shfl_down(best, off, 64);
            int oi = __shfl_down(bidx, off, 64);
            if (ov < best || (ov == best && oi < bidx)) { best = ov; bidx = oi; }
        }
        if (lane == 0) idx_out[mn] = bidx;
    }
}

// ---------------------------------------------------------------------------
// Outputs: z_vq gather-scatter, indices as float, loss reduction, histogram.
__global__ __launch_bounds__(256) void output_kernel(
        const float* __restrict__ z, const float* __restrict__ cb,
        const int* __restrict__ idx_in, float* __restrict__ out) {
    const int tid = threadIdx.x;
    const int n = blockIdx.x * 256 + tid;
    const int m = blockIdx.y;
    const int b = n >> 10;
    const int hw = n & (HWD - 1);
    const int idx = idx_in[m * NN + n];

    out[IDX_OFF + m * NN + n] = (float)idx;

    const float* cr = cb + ((size_t)m * NE + (size_t)idx) * ED;
    const float* zbase = z + (((size_t)(b * CC + m * ED)) << 10) + hw;
    float* ob = out + (((size_t)(b * CC + m * ED)) << 10) + hw;

    double acc = 0.0;
#pragma unroll
    for (int d = 0; d < ED; ++d) {
        float c = cr[d];
        float zv = zbase[(size_t)d << 10];
        ob[(size_t)d << 10] = c;                 // STE forward value == zq
        float diff = c - zv;
        acc += (double)diff * (double)diff;
    }

    __shared__ int hist[NE];
#pragma unroll
    for (int i = 0; i < 4; ++i) hist[tid + i * 256] = 0;
    __syncthreads();
    atomicAdd(&hist[idx], 1);

#pragma unroll
    for (int off = 32; off >= 1; off >>= 1)
        acc += __shfl_down(acc, off, 64);
    __shared__ double wsum[4];
    if ((tid & 63) == 0) wsum[tid >> 6] = acc;
    __syncthreads();
    if (tid == 0) {
        double t = wsum[0] + wsum[1] + wsum[2] + wsum[3];
        atomicAdd(out + LOSS_OFF, (float)(t * (1.25 / 1048576.0)));
    }
#pragma unroll
    for (int i = 0; i < 4; ++i) {
        int v = hist[tid + i * 256];
        if (v) atomicAdd(out + BIN_OFF + tid + i * 256, (float)v);
    }
}

// ---------------------------------------------------------------------------
extern "C" void kernel_launch(void* const* d_in, const int* in_sizes, int n_in,
                              void* d_out, int out_size, void* d_ws, size_t ws_size,
                              hipStream_t stream) {
    const float* z = (const float*)d_in[0];    // (16,512,32,32) fp32
    const float* cb = (const float*)d_in[1];   // (8,1024,64) fp32
    float* out = (float*)d_out;
    char* ws = (char*)d_ws;
    float* Bhat = (float*)(ws + WS_B);
    int* idxw = (int*)(ws + WS_IDX);
    int* cnt = (int*)(ws + WS_CNT);
    int* list = (int*)(ws + WS_LIST);
    uint4* Bmat = (uint4*)(ws + WS_BMAT);

    hipMemsetAsync(cnt, 0, 4, stream);
    hipMemsetAsync(out + LOSS_OFF, 0, 4, stream);
    hipMemsetAsync(out + BIN_OFF, 0, NE * sizeof(float), stream);

    prep_kernel<<<dim3(MM * NE / 256), dim3(256), 0, stream>>>(cb, Bhat);
    prep_bmat<<<dim3(768), dim3(256), 0, stream>>>(cb, Bmat);
    argmin_kernel<<<dim3(NN / 128, MM), dim3(256), 0, stream>>>(z, Bmat, Bhat,
                                                                idxw, cnt, list);
    emul_kernel<<<dim3(128), dim3(256), 0, stream>>>(z, cb, Bhat, cnt, list, idxw);
    output_kernel<<<dim3(NN / 256, MM), dim3(256), 0, stream>>>(z, cb, idxw, out);
}

// Round 4
// 280.645 us; speedup vs baseline: 2.4943x; 1.2229x over previous
//
#include <hip/hip_runtime.h>
#include <cfloat>

// Problem constants
#define BS 16
#define CC 512
#define HWD 1024      // h*w
#define NN 16384      // BS*HWD rows
#define MM 8          // sub-codebooks
#define NE 1024       // codes per sub-codebook
#define ED 64         // code dim

// d_out layout (all read back as float32):
//   [0, 8388608)            z_vq  (bs,c,h,w)
//   [8388608]               loss
//   [8388609, 8519681)      min_encoding_indices (m*N), as float
//   [8519681, 8520705)      bin_count (n_e), as float
#define LOSS_OFF 8388608
#define IDX_OFF  8388609
#define BIN_OFF  8519681

// flag margin: ref fp32 quantization perturbs d by <=~1.5e-5; phase-1 err ~1e-6
#define TAU 4e-5f

// workspace byte offsets
#define WS_B    0             // float[MM*NE] emulated ||e||^2 (np pairwise)
#define WS_IDX  32768         // int[MM*NN]
#define WS_CNT  557056        // int flag counter
#define WS_LIST 557072        // int[MM*NN] flagged rows
#define WS_BMAT 1081360       // uint4[8*12*32*64] = 3 MB, bf16 frag-order B

typedef __attribute__((ext_vector_type(8))) short bf16x8;
typedef __attribute__((ext_vector_type(16))) float f32x16;

// ---- bf16 helpers (manual RNE, no API dependency) -------------------------
__device__ __forceinline__ unsigned short f2bf(float f) {
    unsigned int u = __float_as_uint(f);
    unsigned int r = (u + 0x7fffu + ((u >> 16) & 1u)) >> 16;
    return (unsigned short)r;
}
__device__ __forceinline__ float bf2f(unsigned short h) {
    return __uint_as_float(((unsigned int)h) << 16);
}

// ---- fp32 ops with contraction disabled (bit-exact IEEE mul/add/sub) ------
__device__ __forceinline__ float mul_rn(float a, float b) {
#pragma clang fp contract(off)
    return a * b;
}
__device__ __forceinline__ float add_rn(float a, float b) {
#pragma clang fp contract(off)
    return a + b;
}
__device__ __forceinline__ float sub_rn(float a, float b) {
#pragma clang fp contract(off)
    return a - b;
}

// numpy FLOAT_pairwise_sum over fl(x_d^2), n=64 (works on LDS or global ptr)
__device__ __forceinline__ float np_sumsq64(const float* x) {
    float r[8];
#pragma unroll
    for (int j = 0; j < 8; ++j) r[j] = mul_rn(x[j], x[j]);
#pragma unroll
    for (int i = 8; i < 64; i += 8) {
#pragma unroll
        for (int j = 0; j < 8; ++j) r[j] = add_rn(r[j], mul_rn(x[i + j], x[i + j]));
    }
    return add_rn(add_rn(add_rn(r[0], r[1]), add_rn(r[2], r[3])),
                  add_rn(add_rn(r[4], r[5]), add_rn(r[6], r[7])));
}

// ---------------------------------------------------------------------------
// prep: emulated np ||e_k||^2 per (m,k)  (used by emul AND as phase-1 norm)
__global__ __launch_bounds__(256) void prep_kernel(const float* __restrict__ cb,
                                                   float* __restrict__ Bhat) {
    int i = blockIdx.x * 256 + threadIdx.x;   // 0..MM*NE-1
    const float4* r4 = (const float4*)(cb + (size_t)i * ED);
    float x[ED];
#pragma unroll
    for (int q = 0; q < 16; ++q) {
        float4 v = r4[q];
        x[q * 4 + 0] = v.x; x[q * 4 + 1] = v.y; x[q * 4 + 2] = v.z; x[q * 4 + 3] = v.w;
    }
    Bhat[i] = np_sumsq64(x);
}

// ---------------------------------------------------------------------------
// prep_bmat: build B in MFMA-fragment order, split bf16 of (-2e).
// Bmat[t] for t = (((m*12 + c)*32 + ct)*64 + lane): one 16-B octet (8 bf16).
// K-chunk c: 0-3 -> eh (pairs with zh); 4-7 -> el (pairs with zh);
//            8-11 -> eh (pairs with zl).  k-within-chunk = 8*(lane>>5)+j.
__global__ __launch_bounds__(256) void prep_bmat(const float* __restrict__ cb,
                                                 uint4* __restrict__ Bmat) {
    int t = blockIdx.x * 256 + threadIdx.x;   // 0 .. 8*12*32*64-1
    int lane = t & 63;
    int ct = (t >> 6) & 31;
    int c = (t >> 11) % 12;
    int m = t / 24576;
    int h = lane >> 5;
    int k = ct * 32 + (lane & 31);            // code index
    int d0 = 16 * (c & 3) + 8 * h;            // dim base of this octet

    const float* e = cb + ((size_t)m * NE + k) * ED + d0;
    unsigned short v[8];
#pragma unroll
    for (int j = 0; j < 8; ++j) {
        float f = -2.0f * e[j];
        unsigned short hi = f2bf(f);
        if (c >= 4 && c < 8) {
            v[j] = f2bf(f - bf2f(hi));        // el
        } else {
            v[j] = hi;                        // eh
        }
    }
    uint4 o;
    o.x = (unsigned)v[0] | ((unsigned)v[1] << 16);
    o.y = (unsigned)v[2] | ((unsigned)v[3] << 16);
    o.z = (unsigned)v[4] | ((unsigned)v[5] << 16);
    o.w = (unsigned)v[6] | ((unsigned)v[7] << 16);
    Bmat[t] = o;
}

// ---------------------------------------------------------------------------
// phase 1: split-bf16 MFMA distance + per-row top-2 margin flagging.
// Block: 256 thr (4 waves), 128 rows (32/wave), all 1024 codes in 8 chunks.
__global__ __launch_bounds__(256, 2) void argmin_kernel(
        const float* __restrict__ z, const uint4* __restrict__ Bmat,
        const float* __restrict__ Bhat, int* __restrict__ idx_out,
        int* __restrict__ cnt, int* __restrict__ list) {
    const int tid = threadIdx.x;
    const int m = blockIdx.y;
    const int row0 = blockIdx.x * 128;
    const int w = tid >> 6;
    const int l = tid & 63;
    const int h = l >> 5;
    const int r5 = l & 31;

    __shared__ uint4 ldsB[12 * 256];     // 48 KB: [c][ctl][lane] 16-B frags
    __shared__ float ldsN[NE];           // 4 KB norms

    // stage norms
    {
        const float4* np4 = (const float4*)(Bhat + m * NE);
        ((float4*)ldsN)[tid] = np4[tid];
    }

    // load this lane's z row and split to bf16 hi/lo octets.
    const int n_mine = row0 + w * 32 + r5;
    const int b = n_mine >> 10;
    const int hw = n_mine & (HWD - 1);
    const float* zbase = z + (((size_t)(b * CC + m * ED)) << 10) + hw;

    bf16x8 zh[4], zl[4];
#pragma unroll
    for (int i = 0; i < 4; ++i) {
        int o = 2 * i + h;
#pragma unroll
        for (int j = 0; j < 8; ++j) {
            float f = zbase[(size_t)(8 * o + j) << 10];
            unsigned short hb = f2bf(f);
            unsigned short lb = f2bf(f - bf2f(hb));
            zh[i][j] = (short)hb;
            zl[i][j] = (short)lb;
        }
    }

    float best[16], sec[16];
    int bidx[16];
#pragma unroll
    for (int s = 0; s < 16; ++s) { best[s] = FLT_MAX; sec[s] = FLT_MAX; bidx[s] = 0; }

    for (int cc = 0; cc < 8; ++cc) {      // col-chunks of 128 codes
        __syncthreads();
#pragma unroll
        for (int c = 0; c < 12; ++c) {
            const uint4* src = Bmat + ((size_t)(m * 12 + c) * 32 + cc * 4) * 64;
            ldsB[c * 256 + tid] = src[tid];
        }
        __syncthreads();

#pragma unroll
        for (int ctl = 0; ctl < 4; ++ctl) {  // col-tiles of 32 codes
            f32x16 acc;
#pragma unroll
            for (int s = 0; s < 16; ++s) acc[s] = 0.0f;

#pragma unroll
            for (int c = 0; c < 12; ++c) {
                bf16x8 bfrag = *(const bf16x8*)&ldsB[c * 256 + ctl * 64 + l];
                bf16x8 afrag = (c < 4) ? zh[c] : ((c < 8) ? zh[c - 4] : zl[c - 8]);
                acc = __builtin_amdgcn_mfma_f32_32x32x16_bf16(afrag, bfrag, acc,
                                                              0, 0, 0);
            }

            const int kcol = cc * 128 + ctl * 32 + r5;   // this lane's code col
            const float norm = ldsN[kcol];
#pragma unroll
            for (int s = 0; s < 16; ++s) {
                float d = acc[s] + norm;
                float t = fmaxf(best[s], d);
                sec[s] = fminf(sec[s], t);
                bool cdl = d < best[s];
                best[s] = fminf(best[s], d);
                bidx[s] = cdl ? kcol : bidx[s];
            }
        }
    }

    // cross-lane top-2 merge over the 32-lane half-group (same rows)
#pragma unroll
    for (int off = 1; off <= 16; off <<= 1) {
#pragma unroll
        for (int s = 0; s < 16; ++s) {
            float ob = __shfl_xor(best[s], off, 64);
            float os = __shfl_xor(sec[s], off, 64);
            int oi = __shfl_xor(bidx[s], off, 64);
            bool take = (ob < best[s]) || (ob == best[s] && oi < bidx[s]);
            float ns = take ? fminf(best[s], os) : fminf(sec[s], ob);
            best[s] = take ? ob : best[s];
            bidx[s] = take ? oi : bidx[s];
            sec[s] = ns;
        }
    }

    // lanes r5<16 write slot s=r5: row = (s&3) + 8*(s>>2) + 4*h  [m74/m101]
#pragma unroll
    for (int s = 0; s < 16; ++s) {
        if (r5 == s) {
            int row = (s & 3) + 8 * (s >> 2) + 4 * h;
            int n = row0 + w * 32 + row;
            int mn = m * NN + n;
            idx_out[mn] = bidx[s];
            if (sec[s] - best[s] < TAU) {
                int p = atomicAdd(cnt, 1);
                list[p] = mn;
            }
        }
    }
}

// ---------------------------------------------------------------------------
// phase 2: bit-exact numpy-fp32 emulation, one BLOCK per flagged row.
// z row in LDS (no register spill); thread t owns codes k = kk*256 + t.
__global__ __launch_bounds__(256) void emul_kernel(
        const float* __restrict__ z, const float* __restrict__ cb,
        const float* __restrict__ Bhat, const int* __restrict__ cnt,
        const int* __restrict__ list, int* __restrict__ idx_out) {
    const int tid = threadIdx.x;
    const int lane = tid & 63;
    const int w = tid >> 6;
    const int total = *cnt;

    __shared__ float zsh[ED];
    __shared__ float rbest[4];
    __shared__ int ridx[4];

    for (int r = blockIdx.x; r < total; r += gridDim.x) {
        const int mn = list[r];
        const int m = mn >> 14;          // NN = 2^14
        const int n = mn & (NN - 1);
        const int b = n >> 10;
        const int hw = n & (HWD - 1);

        __syncthreads();                 // zsh/rbest safe to overwrite
        if (tid < ED) {
            const float* zbase = z + (((size_t)(b * CC + m * ED)) << 10) + hw;
            zsh[tid] = zbase[(size_t)tid << 10];
        }
        __syncthreads();

        const float A = np_sumsq64(zsh);   // same value in every thread

        const float* cbm = cb + (size_t)m * NE * ED;
        const float* Bm = Bhat + m * NE;
        float best = FLT_MAX;
        int bidx = NE;
#pragma unroll
        for (int kk = 0; kk < 4; ++kk) {
            const int k = kk * 256 + tid;
            const float4* cr4 = (const float4*)(cbm + (size_t)k * ED);
            // numpy einsum sum_of_products_contig_two, SSE npyv (no FMA)
            float v0 = 0.f, v1 = 0.f, v2 = 0.f, v3 = 0.f;
#pragma unroll
            for (int t = 0; t < 4; ++t) {
                float4 e0 = cr4[t * 4 + 0];
                float4 e1 = cr4[t * 4 + 1];
                float4 e2 = cr4[t * 4 + 2];
                float4 e3 = cr4[t * 4 + 3];
                const int d0 = 16 * t;
                v0 = add_rn(mul_rn(zsh[d0 + 0], e0.x),
                     add_rn(mul_rn(zsh[d0 + 4], e1.x),
                     add_rn(mul_rn(zsh[d0 + 8], e2.x),
                     add_rn(mul_rn(zsh[d0 + 12], e3.x), v0))));
                v1 = add_rn(mul_rn(zsh[d0 + 1], e0.y),
                     add_rn(mul_rn(zsh[d0 + 5], e1.y),
                     add_rn(mul_rn(zsh[d0 + 9], e2.y),
                     add_rn(mul_rn(zsh[d0 + 13], e3.y), v1))));
                v2 = add_rn(mul_rn(zsh[d0 + 2], e0.z),
                     add_rn(mul_rn(zsh[d0 + 6], e1.z),
                     add_rn(mul_rn(zsh[d0 + 10], e2.z),
                     add_rn(mul_rn(zsh[d0 + 14], e3.z), v2))));
                v3 = add_rn(mul_rn(zsh[d0 + 3], e0.w),
                     add_rn(mul_rn(zsh[d0 + 7], e1.w),
                     add_rn(mul_rn(zsh[d0 + 11], e2.w),
                     add_rn(mul_rn(zsh[d0 + 15], e3.w), v3))));
            }
            float C = add_rn(add_rn(v0, v1), add_rn(v2, v3));
            float dk = sub_rn(add_rn(A, Bm[k]), mul_rn(2.0f, C));
            if (dk < best || (dk == best && k < bidx)) { best = dk; bidx = k; }
        }
        // wave reduce, first-index tie-break
#pragma unroll
        for (int off = 32; off >= 1; off >>= 1) {
            float ov = __shfl_down(best, off, 64);
            int oi = __shfl_down(bidx, off, 64);
            if (ov < best || (ov == best && oi < bidx)) { best = ov; bidx = oi; }
        }
        if (lane == 0) { rbest[w] = best; ridx[w] = bidx; }
        __syncthreads();
        if (tid == 0) {
            float bb = rbest[0]; int bi = ridx[0];
#pragma unroll
            for (int i = 1; i < 4; ++i) {
                if (rbest[i] < bb || (rbest[i] == bb && ridx[i] < bi)) {
                    bb = rbest[i]; bi = ridx[i];
                }
            }
            idx_out[mn] = bi;
        }
    }
}

// ---------------------------------------------------------------------------
// Outputs: z_vq gather-scatter, indices as float, loss reduction, histogram.
__global__ __launch_bounds__(256) void output_kernel(
        const float* __restrict__ z, const float* __restrict__ cb,
        const int* __restrict__ idx_in, float* __restrict__ out) {
    const int tid = threadIdx.x;
    const int n = blockIdx.x * 256 + tid;
    const int m = blockIdx.y;
    const int b = n >> 10;
    const int hw = n & (HWD - 1);
    const int idx = idx_in[m * NN + n];

    out[IDX_OFF + m * NN + n] = (float)idx;

    const float* cr = cb + ((size_t)m * NE + (size_t)idx) * ED;
    const float* zbase = z + (((size_t)(b * CC + m * ED)) << 10) + hw;
    float* ob = out + (((size_t)(b * CC + m * ED)) << 10) + hw;

    double acc = 0.0;
#pragma unroll
    for (int d = 0; d < ED; ++d) {
        float c = cr[d];
        float zv = zbase[(size_t)d << 10];
        ob[(size_t)d << 10] = c;                 // STE forward value == zq
        float diff = c - zv;
        acc += (double)diff * (double)diff;
    }

    __shared__ int hist[NE];
#pragma unroll
    for (int i = 0; i < 4; ++i) hist[tid + i * 256] = 0;
    __syncthreads();
    atomicAdd(&hist[idx], 1);

#pragma unroll
    for (int off = 32; off >= 1; off >>= 1)
        acc += __shfl_down(acc, off, 64);
    __shared__ double wsum[4];
    if ((tid & 63) == 0) wsum[tid >> 6] = acc;
    __syncthreads();
    if (tid == 0) {
        double t = wsum[0] + wsum[1] + wsum[2] + wsum[3];
        atomicAdd(out + LOSS_OFF, (float)(t * (1.25 / 1048576.0)));
    }
#pragma unroll
    for (int i = 0; i < 4; ++i) {
        int v = hist[tid + i * 256];
        if (v) atomicAdd(out + BIN_OFF + tid + i * 256, (float)v);
    }
}

// ---------------------------------------------------------------------------
extern "C" void kernel_launch(void* const* d_in, const int* in_sizes, int n_in,
                              void* d_out, int out_size, void* d_ws, size_t ws_size,
                              hipStream_t stream) {
    const float* z = (const float*)d_in[0];    // (16,512,32,32) fp32
    const float* cb = (const float*)d_in[1];   // (8,1024,64) fp32
    float* out = (float*)d_out;
    char* ws = (char*)d_ws;
    float* Bhat = (float*)(ws + WS_B);
    int* idxw = (int*)(ws + WS_IDX);
    int* cnt = (int*)(ws + WS_CNT);
    int* list = (int*)(ws + WS_LIST);
    uint4* Bmat = (uint4*)(ws + WS_BMAT);

    hipMemsetAsync(cnt, 0, 4, stream);
    hipMemsetAsync(out + LOSS_OFF, 0, 4, stream);
    hipMemsetAsync(out + BIN_OFF, 0, NE * sizeof(float), stream);

    prep_kernel<<<dim3(MM * NE / 256), dim3(256), 0, stream>>>(cb, Bhat);
    prep_bmat<<<dim3(768), dim3(256), 0, stream>>>(cb, Bmat);
    argmin_kernel<<<dim3(NN / 128, MM), dim3(256), 0, stream>>>(z, Bmat, Bhat,
                                                                idxw, cnt, list);
    emul_kernel<<<dim3(2048), dim3(256), 0, stream>>>(z, cb, Bhat, cnt, list, idxw);
    output_kernel<<<dim3(NN / 256, MM), dim3(256), 0, stream>>>(z, cb, idxw, out);
}

// Round 5
// 241.197 us; speedup vs baseline: 2.9022x; 1.1636x over previous
//
#include <hip/hip_runtime.h>
#include <cfloat>

// Problem constants
#define BS 16
#define CC 512
#define HWD 1024      // h*w
#define NN 16384      // BS*HWD rows
#define MM 8          // sub-codebooks
#define NE 1024       // codes per sub-codebook
#define ED 64         // code dim

// d_out layout (all read back as float32):
//   [0, 8388608)            z_vq  (bs,c,h,w)
//   [8388608]               loss
//   [8388609, 8519681)      min_encoding_indices (m*N), as float
//   [8519681, 8520705)      bin_count (n_e), as float
#define LOSS_OFF 8388608
#define IDX_OFF  8388609
#define BIN_OFF  8519681

// flag margin: ref fp32 quantization perturbs d by <=~1.5e-5; phase-1 err ~3e-6
#define TAU 4e-5f

// workspace byte offsets
#define WS_B    0             // float[MM*NE] emulated ||e||^2 (np pairwise)
#define WS_IDX  32768         // int[MM*NN]
#define WS_CNT  557056        // int flag counter
#define WS_LIST 557072        // int[MM*NN] flagged rows
#define WS_BMAT 1081360       // uint4[8*13*32*64] = 3.25 MB, bf16 frag-order B

typedef __attribute__((ext_vector_type(8))) short bf16x8;
typedef __attribute__((ext_vector_type(16))) float f32x16;

// ---- bf16 helpers (manual RNE, no API dependency) -------------------------
__device__ __forceinline__ unsigned short f2bf(float f) {
    unsigned int u = __float_as_uint(f);
    unsigned int r = (u + 0x7fffu + ((u >> 16) & 1u)) >> 16;
    return (unsigned short)r;
}
__device__ __forceinline__ float bf2f(unsigned short h) {
    return __uint_as_float(((unsigned int)h) << 16);
}
__device__ __forceinline__ unsigned umin(unsigned a, unsigned b) { return a < b ? a : b; }
__device__ __forceinline__ unsigned umax(unsigned a, unsigned b) { return a > b ? a : b; }
__device__ __forceinline__ unsigned umin3(unsigned a, unsigned b, unsigned c) {
    return umin(umin(a, b), c);
}

// ---- fp32 ops with contraction disabled (bit-exact IEEE mul/add/sub) ------
__device__ __forceinline__ float mul_rn(float a, float b) {
#pragma clang fp contract(off)
    return a * b;
}
__device__ __forceinline__ float add_rn(float a, float b) {
#pragma clang fp contract(off)
    return a + b;
}
__device__ __forceinline__ float sub_rn(float a, float b) {
#pragma clang fp contract(off)
    return a - b;
}

// numpy FLOAT_pairwise_sum over fl(x_d^2), n=64 (works on LDS or global ptr)
__device__ __forceinline__ float np_sumsq64(const float* x) {
    float r[8];
#pragma unroll
    for (int j = 0; j < 8; ++j) r[j] = mul_rn(x[j], x[j]);
#pragma unroll
    for (int i = 8; i < 64; i += 8) {
#pragma unroll
        for (int j = 0; j < 8; ++j) r[j] = add_rn(r[j], mul_rn(x[i + j], x[i + j]));
    }
    return add_rn(add_rn(add_rn(r[0], r[1]), add_rn(r[2], r[3])),
                  add_rn(add_rn(r[4], r[5]), add_rn(r[6], r[7])));
}

// ---------------------------------------------------------------------------
// prep: emulated np ||e_k||^2 per (m,k) + output/counter zeroing
__global__ __launch_bounds__(256) void prep_kernel(const float* __restrict__ cb,
                                                   float* __restrict__ Bhat,
                                                   float* __restrict__ out,
                                                   int* __restrict__ cnt) {
    int i = blockIdx.x * 256 + threadIdx.x;   // 0..MM*NE-1
    if (i == 0) { out[LOSS_OFF] = 0.0f; *cnt = 0; }
    if (i < NE) out[BIN_OFF + i] = 0.0f;
    const float4* r4 = (const float4*)(cb + (size_t)i * ED);
    float x[ED];
#pragma unroll
    for (int q = 0; q < 16; ++q) {
        float4 v = r4[q];
        x[q * 4 + 0] = v.x; x[q * 4 + 1] = v.y; x[q * 4 + 2] = v.z; x[q * 4 + 3] = v.w;
    }
    Bhat[i] = np_sumsq64(x);
}

// ---------------------------------------------------------------------------
// prep_bmat: build codebook A-operand fragments, split bf16 of (-2e), plus a
// 13th K-chunk carrying {bf16(||e||^2), 1.0} to fold norm + shift into MFMA.
// Bmat[t], t = (((m*13 + c)*32 + ct)*64 + lane): one 16-B octet (8 bf16).
// c 0-3: eh (pairs zh); 4-7: el (pairs zh); 8-11: eh (pairs zl); 12: norm.
// code = ct*32 + (lane&31); k-within-chunk = 8*(lane>>5)+j.
__global__ __launch_bounds__(256) void prep_bmat(const float* __restrict__ cb,
                                                 const float* __restrict__ Bhat,
                                                 uint4* __restrict__ Bmat) {
    int t = blockIdx.x * 256 + threadIdx.x;   // 0 .. 8*13*2048-1
    int lane = t & 63;
    int ct = (t >> 6) & 31;
    int rem = t >> 11;
    int c = rem % 13;
    int m = rem / 13;
    int h = lane >> 5;
    int k = ct * 32 + (lane & 31);            // code index

    unsigned short v[8];
#pragma unroll
    for (int j = 0; j < 8; ++j) v[j] = 0;

    if (c < 12) {
        int d0 = 16 * (c & 3) + 8 * h;        // dim base of this octet
        const float* e = cb + ((size_t)m * NE + k) * ED + d0;
#pragma unroll
        for (int j = 0; j < 8; ++j) {
            float f = -2.0f * e[j];
            unsigned short hi = f2bf(f);
            v[j] = (c >= 4 && c < 8) ? f2bf(f - bf2f(hi)) : hi;
        }
    } else if (h == 0) {
        v[0] = f2bf(Bhat[m * NE + k]);        // + ||e||^2
        v[1] = 0x3F80;                        // + 1.0 shift (exact in bf16)
    }
    uint4 o;
    o.x = (unsigned)v[0] | ((unsigned)v[1] << 16);
    o.y = (unsigned)v[2] | ((unsigned)v[3] << 16);
    o.z = (unsigned)v[4] | ((unsigned)v[5] << 16);
    o.w = (unsigned)v[6] | ((unsigned)v[7] << 16);
    Bmat[t] = o;
}

// ---------------------------------------------------------------------------
// phase 1: split-bf16 MFMA distance, A=codes / B=z-rows.
// Block: 512 thr (8 waves), 256 rows (32/wave), 1024 codes in 16 groups of 64.
// d'' = 1 + ||e||^2 - 2 z.e computed entirely in MFMA; per-lane packed-u32
// top-2 tournament over its 16 code-slots; 1-level h-merge at the end.
__global__ __launch_bounds__(512, 4) void argmin_kernel(
        const float* __restrict__ z, const uint4* __restrict__ Bmat,
        int* __restrict__ idx_out, int* __restrict__ cnt,
        int* __restrict__ list) {
    const int tid = threadIdx.x;
    const int m = blockIdx.y;
    const int row0 = blockIdx.x * 256;
    const int w = tid >> 6;
    const int l = tid & 63;
    const int h = l >> 5;
    const int r5 = l & 31;

    __shared__ uint4 ldsB[2][13 * 2 * 64];    // 2 x 26 KB

    // z row -> B-operand bf16 hi/lo octets (row = col j = lane&31)
    const int n_mine = row0 + w * 32 + r5;
    const int b = n_mine >> 10;
    const int hw = n_mine & (HWD - 1);
    const float* zbase = z + (((size_t)(b * CC + m * ED)) << 10) + hw;

    bf16x8 zh[4], zl[4];
#pragma unroll
    for (int i = 0; i < 4; ++i) {
        int o = 2 * i + h;
#pragma unroll
        for (int j = 0; j < 8; ++j) {
            float f = zbase[(size_t)(8 * o + j) << 10];
            unsigned short hb = f2bf(f);
            unsigned short lb = f2bf(f - bf2f(hb));
            zh[i][j] = (short)hb;
            zl[i][j] = (short)lb;
        }
    }
    bf16x8 ones12 = {0, 0, 0, 0, 0, 0, 0, 0};
    if (h == 0) { ones12[0] = (short)0x3F80; ones12[1] = (short)0x3F80; }

    unsigned rbm = 0xFFFFFFF0u, rsec = 0xFFFFFFFFu, rinfo = 0;

    // async stage of group g into buffer bufi (26 segments over 8 waves)
    auto stage = [&](int g, int bufi) {
        for (int seg = w; seg < 26; seg += 8) {
            int c = seg >> 1, ct2 = seg & 1;
            const uint4* src = Bmat +
                ((size_t)((m * 13 + c) * 32 + (g * 2 + ct2)) << 6) + l;
            uint4* dst = &ldsB[bufi][(c * 2 + ct2) * 64];
            __builtin_amdgcn_global_load_lds(
                (const __attribute__((address_space(1))) unsigned int*)src,
                (__attribute__((address_space(3))) unsigned int*)dst, 16, 0, 0);
        }
    };

    stage(0, 0);
    __syncthreads();
    int buf = 0;
    for (int g = 0; g < 16; ++g) {
        if (g < 15) stage(g + 1, buf ^ 1);

#pragma unroll
        for (int ctl = 0; ctl < 2; ++ctl) {
            f32x16 acc;
#pragma unroll
            for (int s = 0; s < 16; ++s) acc[s] = 0.0f;
#pragma unroll
            for (int c = 0; c < 13; ++c) {
                bf16x8 af = *(const bf16x8*)&ldsB[buf][(c * 2 + ctl) * 64 + l];
                bf16x8 bfr = (c < 8) ? zh[c & 3] : ((c < 12) ? zl[c & 3] : ones12);
                acc = __builtin_amdgcn_mfma_f32_32x32x16_bf16(af, bfr, acc, 0, 0, 0);
            }
            // pack: positive floats ~[0.8,1.2]; low 4 mantissa bits carry s
            unsigned u[16];
#pragma unroll
            for (int s = 0; s < 16; ++s)
                u[s] = (__float_as_uint(acc[s]) & 0xFFFFFFF0u) | (unsigned)s;
            // top-2 tournament of 16
            unsigned b0 = umin(u[0], u[1]),  s0 = umax(u[0], u[1]);
            unsigned b1 = umin(u[2], u[3]),  s1 = umax(u[2], u[3]);
            unsigned b2 = umin(u[4], u[5]),  s2 = umax(u[4], u[5]);
            unsigned b3 = umin(u[6], u[7]),  s3 = umax(u[6], u[7]);
            unsigned b4 = umin(u[8], u[9]),  s4 = umax(u[8], u[9]);
            unsigned b5 = umin(u[10], u[11]), s5 = umax(u[10], u[11]);
            unsigned b6 = umin(u[12], u[13]), s6 = umax(u[12], u[13]);
            unsigned b7 = umin(u[14], u[15]), s7 = umax(u[14], u[15]);
            unsigned B0 = umin(b0, b1), S0 = umin3(umax(b0, b1), s0, s1);
            unsigned B1 = umin(b2, b3), S1 = umin3(umax(b2, b3), s2, s3);
            unsigned B2 = umin(b4, b5), S2 = umin3(umax(b4, b5), s4, s5);
            unsigned B3 = umin(b6, b7), S3 = umin3(umax(b6, b7), s6, s7);
            unsigned C0 = umin(B0, B1), T0 = umin3(umax(B0, B1), S0, S1);
            unsigned C1 = umin(B2, B3), T1 = umin3(umax(B2, B3), S2, S3);
            unsigned bt = umin(C0, C1), st = umin3(umax(C0, C1), T0, T1);
            // running merge (ties -> flagged later, emul resolves exactly)
            unsigned tile = (unsigned)(g * 2 + ctl);
            bool take = bt < rbm;
            unsigned other = take ? rbm : bt;
            rsec = umin3(rsec, st, other);
            unsigned newinfo = (tile << 4) | (bt & 15u);
            rbm = take ? bt : rbm;
            rinfo = take ? newinfo : rinfo;
        }
        __syncthreads();
        buf ^= 1;
    }

    // decode k, merge h-halves (lane ^ 32), write
    {
        unsigned ss = rinfo & 15u, tile = rinfo >> 4;
        int k = (int)(tile * 32 + (ss & 3u) + 8u * (ss >> 2) + 4u * (unsigned)h);
        unsigned orbm = __shfl_xor(rbm, 32, 64);
        int ok = __shfl_xor(k, 32, 64);
        unsigned orsec = __shfl_xor(rsec, 32, 64);
        bool take = orbm < rbm;
        unsigned lose = take ? rbm : orbm;
        unsigned fb = take ? orbm : rbm;
        int fk = take ? ok : k;
        unsigned fs = umin3(rsec, orsec, lose);
        if (l < 32) {
            int mn = m * NN + n_mine;
            idx_out[mn] = fk;
            float margin = __uint_as_float(fs & 0xFFFFFFF0u) -
                           __uint_as_float(fb & 0xFFFFFFF0u);
            if (margin < TAU) {
                int p = atomicAdd(cnt, 1);
                list[p] = mn;
            }
        }
    }
}

// ---------------------------------------------------------------------------
// phase 2: bit-exact numpy-fp32 emulation, one BLOCK per flagged row.
__global__ __launch_bounds__(256) void emul_kernel(
        const float* __restrict__ z, const float* __restrict__ cb,
        const float* __restrict__ Bhat, const int* __restrict__ cnt,
        const int* __restrict__ list, int* __restrict__ idx_out) {
    const int tid = threadIdx.x;
    const int lane = tid & 63;
    const int w = tid >> 6;
    const int total = *cnt;

    __shared__ float zsh[ED];
    __shared__ float rbest[4];
    __shared__ int ridx[4];

    for (int r = blockIdx.x; r < total; r += gridDim.x) {
        const int mn = list[r];
        const int m = mn >> 14;          // NN = 2^14
        const int n = mn & (NN - 1);
        const int b = n >> 10;
        const int hw = n & (HWD - 1);

        __syncthreads();                 // zsh/rbest safe to overwrite
        if (tid < ED) {
            const float* zbase = z + (((size_t)(b * CC + m * ED)) << 10) + hw;
            zsh[tid] = zbase[(size_t)tid << 10];
        }
        __syncthreads();

        const float A = np_sumsq64(zsh);   // same value in every thread

        const float* cbm = cb + (size_t)m * NE * ED;
        const float* Bm = Bhat + m * NE;
        float best = FLT_MAX;
        int bidx = NE;
#pragma unroll
        for (int kk = 0; kk < 4; ++kk) {
            const int k = kk * 256 + tid;
            const float4* cr4 = (const float4*)(cbm + (size_t)k * ED);
            // numpy einsum sum_of_products_contig_two, SSE npyv (no FMA)
            float v0 = 0.f, v1 = 0.f, v2 = 0.f, v3 = 0.f;
#pragma unroll
            for (int t = 0; t < 4; ++t) {
                float4 e0 = cr4[t * 4 + 0];
                float4 e1 = cr4[t * 4 + 1];
                float4 e2 = cr4[t * 4 + 2];
                float4 e3 = cr4[t * 4 + 3];
                const int d0 = 16 * t;
                v0 = add_rn(mul_rn(zsh[d0 + 0], e0.x),
                     add_rn(mul_rn(zsh[d0 + 4], e1.x),
                     add_rn(mul_rn(zsh[d0 + 8], e2.x),
                     add_rn(mul_rn(zsh[d0 + 12], e3.x), v0))));
                v1 = add_rn(mul_rn(zsh[d0 + 1], e0.y),
                     add_rn(mul_rn(zsh[d0 + 5], e1.y),
                     add_rn(mul_rn(zsh[d0 + 9], e2.y),
                     add_rn(mul_rn(zsh[d0 + 13], e3.y), v1))));
                v2 = add_rn(mul_rn(zsh[d0 + 2], e0.z),
                     add_rn(mul_rn(zsh[d0 + 6], e1.z),
                     add_rn(mul_rn(zsh[d0 + 10], e2.z),
                     add_rn(mul_rn(zsh[d0 + 14], e3.z), v2))));
                v3 = add_rn(mul_rn(zsh[d0 + 3], e0.w),
                     add_rn(mul_rn(zsh[d0 + 7], e1.w),
                     add_rn(mul_rn(zsh[d0 + 11], e2.w),
                     add_rn(mul_rn(zsh[d0 + 15], e3.w), v3))));
            }
            float C = add_rn(add_rn(v0, v1), add_rn(v2, v3));
            float dk = sub_rn(add_rn(A, Bm[k]), mul_rn(2.0f, C));
            if (dk < best || (dk == best && k < bidx)) { best = dk; bidx = k; }
        }
        // wave reduce, first-index tie-break
#pragma unroll
        for (int off = 32; off >= 1; off >>= 1) {
            float ov = __shfl_down(best, off, 64);
            int oi = __shfl_down(bidx, off, 64);
            if (ov < best || (ov == best && oi < bidx)) { best = ov; bidx = oi; }
        }
        if (lane == 0) { rbest[w] = best; ridx[w] = bidx; }
        __syncthreads();
        if (tid == 0) {
            float bb = rbest[0]; int bi = ridx[0];
#pragma unroll
            for (int i = 1; i < 4; ++i) {
                if (rbest[i] < bb || (rbest[i] == bb && ridx[i] < bi)) {
                    bb = rbest[i]; bi = ridx[i];
                }
            }
            idx_out[mn] = bi;
        }
    }
}

// ---------------------------------------------------------------------------
// Outputs: z_vq gather-scatter, indices as float, loss reduction, histogram.
__global__ __launch_bounds__(256) void output_kernel(
        const float* __restrict__ z, const float* __restrict__ cb,
        const int* __restrict__ idx_in, float* __restrict__ out) {
    const int tid = threadIdx.x;
    const int n = blockIdx.x * 256 + tid;
    const int m = blockIdx.y;
    const int b = n >> 10;
    const int hw = n & (HWD - 1);
    const int idx = idx_in[m * NN + n];

    out[IDX_OFF + m * NN + n] = (float)idx;

    const float* cr = cb + ((size_t)m * NE + (size_t)idx) * ED;
    const float* zbase = z + (((size_t)(b * CC + m * ED)) << 10) + hw;
    float* ob = out + (((size_t)(b * CC + m * ED)) << 10) + hw;

    double acc = 0.0;
#pragma unroll
    for (int d = 0; d < ED; ++d) {
        float c = cr[d];
        float zv = zbase[(size_t)d << 10];
        ob[(size_t)d << 10] = c;                 // STE forward value == zq
        float diff = c - zv;
        acc += (double)diff * (double)diff;
    }

    __shared__ int hist[NE];
#pragma unroll
    for (int i = 0; i < 4; ++i) hist[tid + i * 256] = 0;
    __syncthreads();
    atomicAdd(&hist[idx], 1);

#pragma unroll
    for (int off = 32; off >= 1; off >>= 1)
        acc += __shfl_down(acc, off, 64);
    __shared__ double wsum[4];
    if ((tid & 63) == 0) wsum[tid >> 6] = acc;
    __syncthreads();
    if (tid == 0) {
        double t = wsum[0] + wsum[1] + wsum[2] + wsum[3];
        atomicAdd(out + LOSS_OFF, (float)(t * (1.25 / 1048576.0)));
    }
#pragma unroll
    for (int i = 0; i < 4; ++i) {
        int v = hist[tid + i * 256];
        if (v) atomicAdd(out + BIN_OFF + tid + i * 256, (float)v);
    }
}

// ---------------------------------------------------------------------------
extern "C" void kernel_launch(void* const* d_in, const int* in_sizes, int n_in,
                              void* d_out, int out_size, void* d_ws, size_t ws_size,
                              hipStream_t stream) {
    const float* z = (const float*)d_in[0];    // (16,512,32,32) fp32
    const float* cb = (const float*)d_in[1];   // (8,1024,64) fp32
    float* out = (float*)d_out;
    char* ws = (char*)d_ws;
    float* Bhat = (float*)(ws + WS_B);
    int* idxw = (int*)(ws + WS_IDX);
    int* cnt = (int*)(ws + WS_CNT);
    int* list = (int*)(ws + WS_LIST);
    uint4* Bmat = (uint4*)(ws + WS_BMAT);

    prep_kernel<<<dim3(MM * NE / 256), dim3(256), 0, stream>>>(cb, Bhat, out, cnt);
    prep_bmat<<<dim3(MM * 13 * 2048 / 256), dim3(256), 0, stream>>>(cb, Bhat, Bmat);
    argmin_kernel<<<dim3(NN / 256, MM), dim3(512), 0, stream>>>(z, Bmat, idxw,
                                                                cnt, list);
    emul_kernel<<<dim3(2048), dim3(256), 0, stream>>>(z, cb, Bhat, cnt, list, idxw);
    output_kernel<<<dim3(NN / 256, MM), dim3(256), 0, stream>>>(z, cb, idxw, out);
}